// Round 1
// baseline (1224.183 us; speedup 1.0000x reference)
//
#include <hip/hip_runtime.h>
#include <hip/hip_bf16.h>

// Problem constants (match reference)
#define NB   8
#define NN   256
#define NM   32
#define NHW  32768

#define CCHUNKS 128           // c-split for parallelism: grid = NB*CCHUNKS = 1024 blocks
#define CK   (NHW / CCHUNKS)  // 256 c per block

// ws layout (floats): ADX[NB*NN*NM] | ADS[NB*NN*NM] | ASN[NB*NN] | ASS[NB*NN] | STGT[NB*NM]
#define OFF_ADX  0
#define OFF_ADS  (NB*NN*NM)
#define OFF_ASN  (2*NB*NN*NM)
#define OFF_ASS  (2*NB*NN*NM + NB*NN)
#define OFF_STGT (2*NB*NN*NM + 2*NB*NN)
#define WS_FLOATS (2*NB*NN*NM + 2*NB*NN + NB*NM)

typedef _Float16 h2 __attribute__((ext_vector_type(2)));
typedef _Float16 h8 __attribute__((ext_vector_type(8)));

__device__ __forceinline__ float DOT2(h2 a, h2 b, float c) {
#if __has_builtin(__builtin_amdgcn_fdot2)
    return __builtin_amdgcn_fdot2(a, b, c, false);
#else
    return c + (float)a[0] * (float)b[0] + (float)a[1] * (float)b[1];
#endif
}

// Main: per (b, c-chunk) block, thread t owns n=t for the whole chunk.
// Accumulates partial  Dx[n][m] = sum_c x*tgt,  Dsig[n][m] = sum_c s*tgt,
// Sneg[n] = sum_c (x + softplus(-x)),  Ssig[n] = sum_c sigmoid(x),  Stgt[m] = sum_c tgt
// into global fp32 accumulators via unsafeAtomicAdd (fire-and-forget).
__global__ __launch_bounds__(256, 4) void cost_main(
    const float* __restrict__ X,   // [NB][NHW][NN]  mask_heatmaps
    const float* __restrict__ T,   // [NB][NM][NHW]  mask_tgt (binary)
    float* __restrict__ ws)
{
    float* __restrict__ ADX  = ws + OFF_ADX;
    float* __restrict__ ADS  = ws + OFF_ADS;
    float* __restrict__ ASN  = ws + OFF_ASN;
    float* __restrict__ ASS  = ws + OFF_ASS;
    float* __restrict__ STGT = ws + OFF_STGT;

    const int blk   = blockIdx.x;
    const int b     = blk / CCHUNKS;
    const int chunk = blk % CCHUNKS;
    const int c0    = chunk * CK;
    const int n     = threadIdx.x;

    // Stage tgt slab [NM][CK] into LDS as f16 (binary values exact in f16).
    __shared__ __align__(16) _Float16 tl[NM][CK];   // 16 KB
    {
        const float* Tb = T + (size_t)b * NM * NHW + c0;
        for (int i = threadIdx.x; i < NM * (CK / 2); i += 256) {
            int c2 = i % (CK / 2);
            int m  = i / (CK / 2);
            float2 v = *(const float2*)(Tb + (size_t)m * NHW + 2 * c2);
            tl[m][2 * c2]     = (_Float16)v.x;
            tl[m][2 * c2 + 1] = (_Float16)v.y;
        }
    }
    __syncthreads();

    float accx[NM], accs[NM];
#pragma unroll
    for (int m = 0; m < NM; ++m) { accx[m] = 0.f; accs[m] = 0.f; }
    float sneg = 0.f, ssig = 0.f;

    const float* Xp = X + ((size_t)b * NHW + c0) * NN + n;

    for (int ct = 0; ct < CK; ct += 8) {
        float xv[8];
#pragma unroll
        for (int j = 0; j < 8; ++j)
            xv[j] = Xp[(size_t)(ct + j) * NN];   // coalesced across lanes (lane=n)

        h2 xh[4], sh[4];
#pragma unroll
        for (int j = 0; j < 8; j += 2) {
            float s01[2];
#pragma unroll
            for (int k = 0; k < 2; ++k) {
                float x = xv[j + k];
                float e = __expf(-fabsf(x));             // e = exp(-|x|) <= 1, no overflow
                float r = __builtin_amdgcn_rcpf(1.f + e);
                float s = (x >= 0.f) ? r : 1.f - r;      // sigmoid(x), stable
                float pos = fmaxf(-x, 0.f) + __logf(1.f + e);  // softplus(-x), stable
                sneg += x + pos;                          // neg = x + softplus(-x)
                ssig += s;
                s01[k] = s;
            }
            xh[j / 2] = h2{(_Float16)xv[j], (_Float16)xv[j + 1]};
            sh[j / 2] = h2{(_Float16)s01[0], (_Float16)s01[1]};
        }

#pragma unroll
        for (int m = 0; m < NM; ++m) {
            h8 tv = *(const h8*)(&tl[m][ct]);    // broadcast ds_read_b128, conflict-free
            h2 t0 = __builtin_shufflevector(tv, tv, 0, 1);
            h2 t1 = __builtin_shufflevector(tv, tv, 2, 3);
            h2 t2 = __builtin_shufflevector(tv, tv, 4, 5);
            h2 t3 = __builtin_shufflevector(tv, tv, 6, 7);
            accx[m] = DOT2(xh[0], t0, accx[m]);
            accx[m] = DOT2(xh[1], t1, accx[m]);
            accx[m] = DOT2(xh[2], t2, accx[m]);
            accx[m] = DOT2(xh[3], t3, accx[m]);
            accs[m] = DOT2(sh[0], t0, accs[m]);
            accs[m] = DOT2(sh[1], t1, accs[m]);
            accs[m] = DOT2(sh[2], t2, accs[m]);
            accs[m] = DOT2(sh[3], t3, accs[m]);
        }
    }

    // Writeback partials (no return value needed -> pipelined RMWs)
    float* adx = ADX + ((size_t)b * NN + n) * NM;
    float* ads = ADS + ((size_t)b * NN + n) * NM;
#pragma unroll
    for (int m = 0; m < NM; ++m) {
        unsafeAtomicAdd(&adx[m], accx[m]);
        unsafeAtomicAdd(&ads[m], accs[m]);
    }
    unsafeAtomicAdd(&ASN[b * NN + n], sneg);
    unsafeAtomicAdd(&ASS[b * NN + n], ssig);

    // Per-m tgt row sums for this chunk (rows are L2-hot from staging)
    if (n < NM) {
        const float* tr = T + (size_t)b * NM * NHW + (size_t)n * NHW + c0;
        float st = 0.f;
        for (int ci = 0; ci < CK; ci += 4) {
            float4 v = *(const float4*)(tr + ci);
            st += v.x + v.y + v.z + v.w;
        }
        unsafeAtomicAdd(&STGT[b * NM + n], st);
    }
}

// Finalize: out[b][n][m] = 2*class + center + 5*cost_mask + 2*cost_dice
__global__ __launch_bounds__(256) void cost_finalize(
    const float* __restrict__ P,    // sem_cls_prob [NB][NN][1]
    const float* __restrict__ CD,   // center_dist [NB][NN][NM]
    const int*   __restrict__ LAB,  // labels [NB][NM], values in {0,1}
    const float* __restrict__ ws,
    float* __restrict__ out)
{
    const float* ADX  = ws + OFF_ADX;
    const float* ADS  = ws + OFF_ADS;
    const float* ASN  = ws + OFF_ASN;
    const float* ASS  = ws + OFF_ASS;
    const float* STGT = ws + OFF_STGT;

    int idx = blockIdx.x * 256 + threadIdx.x;   // 0 .. NB*NN*NM-1
    int m = idx & (NM - 1);
    int n = (idx >> 5) & (NN - 1);
    int b = idx >> 13;

    float dx = ADX[idx];
    float ds = ADS[idx];
    float sn = ASN[b * NN + n];
    float ss = ASS[b * NN + n];
    float st = STGT[b * NM + m];

    float p   = P[b * NN + n];
    int   lab = LAB[b * NM + m];
    float cls = lab ? -p : (p - 1.f);                       // -gather(cat(1-p, p), lab)

    float cmask = (sn - dx) * (1.f / (float)NHW);           // (Σneg - Σ x·tgt)/HW
    float dice  = 1.f - (2.f * ds + 1.f) / (ss + st + 1.f); // 1 - (2Σs·tgt+1)/(Σs+Σtgt+1)

    out[idx] = 2.f * cls + CD[idx] + 5.f * cmask + 2.f * dice;
}

extern "C" void kernel_launch(void* const* d_in, const int* in_sizes, int n_in,
                              void* d_out, int out_size, void* d_ws, size_t ws_size,
                              hipStream_t stream) {
    const float* P   = (const float*)d_in[0];  // sem_cls_prob
    const float* CD  = (const float*)d_in[1];  // center_dist
    const float* X   = (const float*)d_in[2];  // mask_heatmaps
    const float* T   = (const float*)d_in[3];  // mask_tgt
    const int*   LAB = (const int*)d_in[4];    // gt_plane_sem_cls_label
    float* out = (float*)d_out;
    float* ws  = (float*)d_ws;

    hipMemsetAsync(d_ws, 0, WS_FLOATS * sizeof(float), stream);
    hipLaunchKernelGGL(cost_main, dim3(NB * CCHUNKS), dim3(256), 0, stream, X, T, ws);
    hipLaunchKernelGGL(cost_finalize, dim3((NB * NN * NM) / 256), dim3(256), 0, stream,
                       P, CD, LAB, ws, out);
}

// Round 2
// 433.555 us; speedup vs baseline: 2.8236x; 2.8236x over previous
//
#include <hip/hip_runtime.h>
#include <hip/hip_bf16.h>

// Problem constants (match reference)
#define NB   8
#define NN   256
#define NM   32
#define NHW  32768

// Decomposition: grid = NB(8) x NT(16 n-tiles of 16) x CCH(4 c-chunks) = 512 blocks
// block = 512 threads = 8 waves; each wave owns CW = 1024 consecutive c.
#define CCH    4
#define CSLAB  (NHW / CCH)     // 8192 c per chunk
#define NT     16
#define WPB    8
#define CW     (CSLAB / WPB)   // 1024 c per wave
#define ITERS  (CW / 32)       // 32 k-steps of 32

// ws layout (floats) -- every cell written exactly once, no memset needed
#define OFF_DXP  0                          // [CCH][NB][NT][16n*32m]
#define SZ_DXP   (CCH*NB*NT*512)
#define OFF_DSP  (OFF_DXP + SZ_DXP)
#define SZ_DSP   SZ_DXP
#define OFF_SNP  (OFF_DSP + SZ_DSP)         // [CCH][NB][NN]
#define SZ_SNP   (CCH*NB*NN)
#define OFF_SSP  (OFF_SNP + SZ_SNP)
#define SZ_SSP   SZ_SNP
#define OFF_STGT (OFF_SSP + SZ_SSP)         // [NB][NM]

typedef _Float16 half8 __attribute__((ext_vector_type(8)));
typedef float    f32x4 __attribute__((ext_vector_type(4)));

// ---------------------------------------------------------------------------
// Pass 0: per-(b,m) target row sums. Also warms T into L3 for cost_main.
__global__ __launch_bounds__(256) void sum_tgt(const float* __restrict__ T,
                                               float* __restrict__ ws) {
    const int blk  = blockIdx.x;            // b*NM + m
    const int tid  = threadIdx.x;
    const int lane = tid & 63;
    const int wave = tid >> 6;
    const float* tp = T + (size_t)blk * NHW;

    float s = 0.f;
    for (int k = 0; k < NHW / (256 * 4); ++k) {           // 32 iters
        float4 v = *(const float4*)(tp + (size_t)k * 1024 + tid * 4);
        s += (v.x + v.y) + (v.z + v.w);
    }
    s += __shfl_down(s, 32);
    s += __shfl_down(s, 16);
    s += __shfl_down(s, 8);
    s += __shfl_down(s, 4);
    s += __shfl_down(s, 2);
    s += __shfl_down(s, 1);

    __shared__ float r4[4];
    if (lane == 0) r4[wave] = s;
    __syncthreads();
    if (tid == 0) ws[OFF_STGT + blk] = (r4[0] + r4[1]) + (r4[2] + r4[3]);
}

// ---------------------------------------------------------------------------
// Pass 1: fragment-direct MFMA contraction.
//   Dx[n,m] = sum_c x*t        Ds[n,m] = sum_c sigmoid(x)*t
//   Sn[n]   = sum_c (x + softplus(-x))   Ss[n] = sum_c sigmoid(x)
// A-frag (16x16x32 f16): lane holds A[row = lane&15][k = (lane>>4)*8 + j]
// B-frag:                lane holds B[col = lane&15][k = (lane>>4)*8 + j]
// D:                     lane reg r -> row = (lane>>4)*4 + r, col = lane&15
__global__ __launch_bounds__(512, 4) void cost_main(
    const float* __restrict__ X,   // [NB][NHW][NN]
    const float* __restrict__ T,   // [NB][NM][NHW]
    float* __restrict__ ws) {
    const int blk  = blockIdx.x;
    const int b    = blk & 7;                 // %8 => XCD-constant per b
    const int rest = blk >> 3;
    const int ch   = rest & 3;
    const int nt   = rest >> 2;

    const int tid  = threadIdx.x;
    const int wave = tid >> 6;
    const int lane = tid & 63;
    const int l16  = lane & 15;
    const int quad = lane >> 4;

    const int n0 = nt * 16;
    const int c0 = ch * CSLAB + wave * CW;

    const float* Xp  = X + ((size_t)b * NHW + c0 + quad * 8) * NN + n0 + l16;
    const float* T0p = T + ((size_t)b * NM + l16)      * NHW + c0 + quad * 8;
    const float* T1p = T + ((size_t)b * NM + l16 + 16) * NHW + c0 + quad * 8;

    f32x4 ax0 = {0.f, 0.f, 0.f, 0.f}, ax1 = {0.f, 0.f, 0.f, 0.f};
    f32x4 as0 = {0.f, 0.f, 0.f, 0.f}, as1 = {0.f, 0.f, 0.f, 0.f};
    float sneg = 0.f, ssig = 0.f;

    for (int it = 0; it < ITERS; ++it) {
        float xv[8];
#pragma unroll
        for (int j = 0; j < 8; ++j)
            xv[j] = Xp[(size_t)j * NN];        // 4 fully-used 64B segments/inst

        float4 ta = *(const float4*)(T0p);
        float4 tb = *(const float4*)(T0p + 4);
        float4 tc = *(const float4*)(T1p);
        float4 td = *(const float4*)(T1p + 4);

        half8 hx, hs, ht0, ht1;
#pragma unroll
        for (int j = 0; j < 8; ++j) {
            float x = xv[j];
            float e = __expf(-fabsf(x));                    // exp(-|x|) <= 1
            float r = __builtin_amdgcn_rcpf(1.f + e);
            float s = (x >= 0.f) ? r : 1.f - r;             // stable sigmoid
            float pos = fmaxf(-x, 0.f) + __logf(1.f + e);   // softplus(-x)
            sneg += x + pos;
            ssig += s;
            hx[j] = (_Float16)x;
            hs[j] = (_Float16)s;
        }
        ht0[0] = (_Float16)ta.x; ht0[1] = (_Float16)ta.y;
        ht0[2] = (_Float16)ta.z; ht0[3] = (_Float16)ta.w;
        ht0[4] = (_Float16)tb.x; ht0[5] = (_Float16)tb.y;
        ht0[6] = (_Float16)tb.z; ht0[7] = (_Float16)tb.w;
        ht1[0] = (_Float16)tc.x; ht1[1] = (_Float16)tc.y;
        ht1[2] = (_Float16)tc.z; ht1[3] = (_Float16)tc.w;
        ht1[4] = (_Float16)td.x; ht1[5] = (_Float16)td.y;
        ht1[6] = (_Float16)td.z; ht1[7] = (_Float16)td.w;

        ax0 = __builtin_amdgcn_mfma_f32_16x16x32_f16(hx, ht0, ax0, 0, 0, 0);
        ax1 = __builtin_amdgcn_mfma_f32_16x16x32_f16(hx, ht1, ax1, 0, 0, 0);
        as0 = __builtin_amdgcn_mfma_f32_16x16x32_f16(hs, ht0, as0, 0, 0, 0);
        as1 = __builtin_amdgcn_mfma_f32_16x16x32_f16(hs, ht1, as1, 0, 0, 0);

        Xp  += (size_t)32 * NN;
        T0p += 32;
        T1p += 32;
    }

    // In-block reduction across 8 waves (LDS atomics: conflict-free in-wave,
    // 8-way serialization across waves -- trivial count).
    __shared__ float redx[512];   // [16 n][32 m]
    __shared__ float reds[512];
    __shared__ float redn[16];
    __shared__ float redss[16];
    redx[tid] = 0.f;
    reds[tid] = 0.f;
    if (tid < 16) { redn[tid] = 0.f; redss[tid] = 0.f; }
    __syncthreads();

#pragma unroll
    for (int r = 0; r < 4; ++r) {
        const int row = quad * 4 + r;
        atomicAdd(&redx[row * 32 + l16],      ax0[r]);
        atomicAdd(&redx[row * 32 + l16 + 16], ax1[r]);
        atomicAdd(&reds[row * 32 + l16],      as0[r]);
        atomicAdd(&reds[row * 32 + l16 + 16], as1[r]);
    }
    sneg += __shfl_down(sneg, 32);
    sneg += __shfl_down(sneg, 16);
    ssig += __shfl_down(ssig, 32);
    ssig += __shfl_down(ssig, 16);
    if (lane < 16) {
        atomicAdd(&redn[l16], sneg);
        atomicAdd(&redss[l16], ssig);
    }
    __syncthreads();

    const size_t base = ((size_t)(ch * NB + b) * NT + nt);
    ws[OFF_DXP + base * 512 + tid] = redx[tid];
    ws[OFF_DSP + base * 512 + tid] = reds[tid];
    if (tid < 16) {
        ws[OFF_SNP + (ch * NB + b) * NN + n0 + tid] = redn[tid];
        ws[OFF_SSP + (ch * NB + b) * NN + n0 + tid] = redss[tid];
    }
}

// ---------------------------------------------------------------------------
// Pass 2: combine 4 chunk partials + class/center/dice formula.
__global__ __launch_bounds__(256) void cost_finalize(
    const float* __restrict__ P,    // [NB][NN][1]
    const float* __restrict__ CD,   // [NB][NN][NM]
    const int*   __restrict__ LAB,  // [NB][NM]
    const float* __restrict__ ws,
    float* __restrict__ out) {
    const int idx = blockIdx.x * 256 + threadIdx.x;   // (b*NN+n)*NM+m
    const int m = idx & 31;
    const int n = (idx >> 5) & 255;
    const int b = idx >> 13;
    const int nt = n >> 4, nl = n & 15;

    float dx = 0.f, ds = 0.f, sn = 0.f, ss = 0.f;
#pragma unroll
    for (int ch = 0; ch < CCH; ++ch) {
        const size_t base = ((size_t)(ch * NB + b) * NT + nt) * 512 + nl * 32 + m;
        dx += ws[OFF_DXP + base];
        ds += ws[OFF_DSP + base];
        sn += ws[OFF_SNP + (ch * NB + b) * NN + n];
        ss += ws[OFF_SSP + (ch * NB + b) * NN + n];
    }
    const float st  = ws[OFF_STGT + b * NM + m];
    const float p   = P[b * NN + n];
    const int   lab = LAB[b * NM + m];
    const float cls = lab ? -p : (p - 1.f);

    const float cmask = (sn - dx) * (1.f / (float)NHW);
    const float dice  = 1.f - (2.f * ds + 1.f) / (ss + st + 1.f);

    out[idx] = 2.f * cls + CD[idx] + 5.f * cmask + 2.f * dice;
}

// ---------------------------------------------------------------------------
extern "C" void kernel_launch(void* const* d_in, const int* in_sizes, int n_in,
                              void* d_out, int out_size, void* d_ws, size_t ws_size,
                              hipStream_t stream) {
    const float* P   = (const float*)d_in[0];  // sem_cls_prob
    const float* CD  = (const float*)d_in[1];  // center_dist
    const float* X   = (const float*)d_in[2];  // mask_heatmaps
    const float* T   = (const float*)d_in[3];  // mask_tgt
    const int*   LAB = (const int*)d_in[4];    // gt_plane_sem_cls_label
    float* out = (float*)d_out;
    float* ws  = (float*)d_ws;

    hipLaunchKernelGGL(sum_tgt, dim3(NB * NM), dim3(256), 0, stream, T, ws);
    hipLaunchKernelGGL(cost_main, dim3(NB * NT * CCH), dim3(512), 0, stream, X, T, ws);
    hipLaunchKernelGGL(cost_finalize, dim3((NB * NN * NM) / 256), dim3(256), 0, stream,
                       P, CD, LAB, ws, out);
}